// Round 4
// baseline (322.796 us; speedup 1.0000x reference)
//
#include <hip/hip_runtime.h>
#include <math.h>

// LinearAutoregressiveHMM fused kernel for MI355X (gfx950).
// B=8192, L=64, C=4, K=8, P=16. One kernel: AR scores (causal conv),
// emission log-probs, HMM forward recursion, argmax state, P-step rollout.
// Block = 256 threads (4 waves); each wave owns 2 batch rows; 8 rows/block.
//
// R4 changes vs R3 (254us, VGPR pinned at 64, 64MB scratch-spill traffic):
//  - The allocator will NOT exceed 64 VGPRs (attributes ignored) -> make the
//    kernel FIT in 64: Phase A split into 4 k-quarters (16 live accs, ~48
//    peak VGPR demand). Spills should vanish (WRITE_SIZE 66MB -> 2MB).
//  - W staged one 8KB quarter at a time (wave-uniform ds_read_b128
//    broadcasts, conflict-free). LDS 38KB -> 29.4KB.
//  - kq loop fully unrolled so e0[k]/e1[k] indexing is compile-time
//    (dynamic-indexed arrays go to scratch on this compiler).
//  - j-loop unroll 2 (unroll 4 was the R3 live-range explosion).
//  - Phases B/C numerics byte-identical to the 3x-passing versions.

namespace {
constexpr int BB   = 8192;
constexpr int LL   = 64;
constexpr int CCH  = 4;
constexpr int KK   = 8;
constexpr int PP   = 16;
constexpr int BPB  = 8;    // batch rows per block
constexpr int NTHR = 256;
}

__global__ __launch_bounds__(256)
void lahmm_fused(const float* __restrict__ em,  const float* __restrict__ trm,
                 const float* __restrict__ ini, const float* __restrict__ mns,
                 const float* __restrict__ cvc, const float* __restrict__ Wg,
                 float* __restrict__ out)
{
    __shared__ __align__(16) float sW[2 * CCH * LL * CCH];    // 2048 f: one k-QUARTER of W (8KB)
    __shared__ __align__(16) float sBuf[BPB][576];            // per b: 144 timesteps x 4 ch
    __shared__ __align__(16) float sElp[BPB][8][KK];          // elp staging, chunks of 8 t
    __shared__ float sLT[KK][KK];      // log(softmax(trans)+1e-8), [j][k]
    __shared__ float sLI[KK];          // log(softmax(init))
    __shared__ float sMean[KK][CCH];
    __shared__ float sVar[KK][CCH];
    __shared__ float sLogdet[KK];
    __shared__ int   sNs[KK];          // argmax of each trans row
    __shared__ unsigned char sChain[KK][PP];  // state chain from each start state

    const int tid   = threadIdx.x;
    const int lane  = tid & 63;
    const int wv    = tid >> 6;
    const int bBase = blockIdx.x * BPB;

    // ---------------- Phase 0: stage em, W quarter 0, small tables ----------------
    const float4* Wg4 = reinterpret_cast<const float4*>(Wg);
    float4* sW4 = reinterpret_cast<float4*>(sW);
    sW4[tid]       = Wg4[tid];          // k-quarter 0 (512 float4)
    sW4[tid + 256] = Wg4[tid + 256];

    const float4* em4 = reinterpret_cast<const float4*>(em);
    float4* sBuf4 = reinterpret_cast<float4*>(&sBuf[0][0]);
#pragma unroll
    for (int r = 0; r < 2; ++r) {
        int idx = tid + r * 256;            // 0..511 covers 8 b x 64 rows
        int bl = idx >> 6, row = idx & 63;
        sBuf4[bl * 144 + 64 + row] = em4[(bBase + bl) * 64 + row];
        sBuf4[bl * 144 + row]      = make_float4(0.f, 0.f, 0.f, 0.f);
    }

    if (tid < KK) {
        // transition row tid: softmax -> log(+1e-8); next-state argmax (raw row: monotone)
        float row[KK];
        float m = -INFINITY;
#pragma unroll
        for (int k = 0; k < KK; ++k) { row[k] = trm[tid * KK + k]; m = fmaxf(m, row[k]); }
        float se = 0.f;
#pragma unroll
        for (int k = 0; k < KK; ++k) se += expf(row[k] - m);
        int best = 0; float bv = row[0];
#pragma unroll
        for (int k = 1; k < KK; ++k) if (row[k] > bv) { bv = row[k]; best = k; }
        sNs[tid] = best;
#pragma unroll
        for (int k = 0; k < KK; ++k) sLT[tid][k] = logf(expf(row[k] - m) / se + 1e-8f);
    } else if (tid == 8) {
        float x[KK]; float m = -INFINITY;
#pragma unroll
        for (int k = 0; k < KK; ++k) { x[k] = ini[k]; m = fmaxf(m, x[k]); }
        float se = 0.f;
#pragma unroll
        for (int k = 0; k < KK; ++k) se += expf(x[k] - m);
#pragma unroll
        for (int k = 0; k < KK; ++k) sLI[k] = logf(expf(x[k] - m) / se);
    } else if (tid >= 32 && tid < 64) {
        int i = tid - 32;                   // 0..31 covers K*C
        (&sMean[0][0])[i] = mns[i];
        (&sVar[0][0])[i]  = expf(cvc[i]) + 1e-6f;
    }
    __syncthreads();
    if (tid < KK) {
        float ld = 0.f;
#pragma unroll
        for (int c = 0; c < CCH; ++c) ld += logf(sVar[tid][c]);
        sLogdet[tid] = ld;
        int s = tid;
#pragma unroll
        for (int p = 0; p < PP; ++p) { s = sNs[s]; sChain[tid][p] = (unsigned char)s; }
    }
    __syncthreads();

    // ---------------- Phase A: AR scores (the 8.6 GFLOP conv) ----------------
    // Four k-quarter passes: 16 live accumulators (fits the 64-VGPR cap).
    const int b0l = wv * 2, b1l = wv * 2 + 1;
    const float4* bv0 = reinterpret_cast<const float4*>(&sBuf[b0l][0]);
    const float4* bv1 = reinterpret_cast<const float4*>(&sBuf[b1l][0]);
    const int t = lane;   // lane owns output timestep t for both its b's

    float e0[KK], e1[KK];
    const float c2pi = 7.3515082656373819f;   // C * log(2*pi)

#pragma unroll
    for (int kq = 0; kq < 4; ++kq) {
        if (kq > 0) {                       // restage next W quarter
            __syncthreads();
            sW4[tid]       = Wg4[kq * 512 + tid];
            sW4[tid + 256] = Wg4[kq * 512 + 256 + tid];
            __syncthreads();
        }
        float acc0[2][CCH], acc1[2][CCH];
#pragma unroll
        for (int q = 0; q < 2; ++q)
#pragma unroll
            for (int c = 0; c < CCH; ++c) { acc0[q][c] = 0.f; acc1[q][c] = 0.f; }

#pragma unroll 2
        for (int j = 0; j < LL; ++j) {
            float4 x0 = bv0[t + j];         // per-lane contiguous b128
            float4 x1 = bv1[t + j];
#pragma unroll
            for (int q = 0; q < 2; ++q) {
#pragma unroll
                for (int c = 0; c < CCH; ++c) {
                    float4 w = sW4[(q * CCH + c) * LL + j];   // uniform -> broadcast
                    float a0 = acc0[q][c], a1 = acc1[q][c];
                    a0 = fmaf(x0.x, w.x, a0); a1 = fmaf(x1.x, w.x, a1);
                    a0 = fmaf(x0.y, w.y, a0); a1 = fmaf(x1.y, w.y, a1);
                    a0 = fmaf(x0.z, w.z, a0); a1 = fmaf(x1.z, w.z, a1);
                    a0 = fmaf(x0.w, w.w, a0); a1 = fmaf(x1.w, w.w, a1);
                    acc0[q][c] = a0; acc1[q][c] = a1;
                }
            }
        }

        // emission log-probs for this k-quarter (numerics identical to R1-R3)
        float4 tg0 = bv0[64 + t], tg1 = bv1[64 + t];
#pragma unroll
        for (int q = 0; q < 2; ++q) {
            const int k = kq * 2 + q;       // compile-time (kq unrolled)
            float mh0 = 0.f, mh1 = 0.f;
#pragma unroll
            for (int c = 0; c < CCH; ++c) {
                float mu = sMean[k][c], va = sVar[k][c];
                float g0 = (c == 0) ? tg0.x : (c == 1) ? tg0.y : (c == 2) ? tg0.z : tg0.w;
                float g1 = (c == 0) ? tg1.x : (c == 1) ? tg1.y : (c == 2) ? tg1.z : tg1.w;
                float d0 = g0 - (mu + acc0[q][c]);
                float d1 = g1 - (mu + acc1[q][c]);
                mh0 += d0 * d0 / va;
                mh1 += d1 * d1 / va;
            }
            e0[k] = -0.5f * (mh0 + sLogdet[k] + c2pi);
            e1[k] = -0.5f * (mh1 + sLogdet[k] + c2pi);
        }
    }

    // ---------------- Phase B: HMM forward recursion ----------------
    // lane = (k,j): k = lane>>3 output state, j = lane&7 source state
    const int kf = lane >> 3, jf = lane & 7;
    const float lt  = sLT[jf][kf];
    const float liJ = sLI[jf], liK = sLI[kf];
    float laP0 = 0.f, laP1 = 0.f;   // la_prev[jf]
    float laN0 = 0.f, laN1 = 0.f;   // la_new[kf]

    for (int ch = 0; ch < 8; ++ch) {
        if ((t >> 3) == ch) {       // stage this chunk's elp rows
            int tt = t & 7;
            float4* dst0 = reinterpret_cast<float4*>(&sElp[b0l][tt][0]);
            dst0[0] = make_float4(e0[0], e0[1], e0[2], e0[3]);
            dst0[1] = make_float4(e0[4], e0[5], e0[6], e0[7]);
            float4* dst1 = reinterpret_cast<float4*>(&sElp[b1l][tt][0]);
            dst1[0] = make_float4(e1[0], e1[1], e1[2], e1[3]);
            dst1[1] = make_float4(e1[4], e1[5], e1[6], e1[7]);
        }
        __syncthreads();
#pragma unroll
        for (int ts = 0; ts < 8; ++ts) {
            if (ch == 0 && ts == 0) {
                laP0 = liJ + sElp[b0l][0][jf];
                laP1 = liJ + sElp[b1l][0][jf];
                laN0 = liK + sElp[b0l][0][kf];
                laN1 = liK + sElp[b1l][0][kf];
            } else {
                float t0 = laP0 + lt, t1 = laP1 + lt;
                float m0 = t0, m1 = t1;
                m0 = fmaxf(m0, __shfl_xor(m0, 1)); m1 = fmaxf(m1, __shfl_xor(m1, 1));
                m0 = fmaxf(m0, __shfl_xor(m0, 2)); m1 = fmaxf(m1, __shfl_xor(m1, 2));
                m0 = fmaxf(m0, __shfl_xor(m0, 4)); m1 = fmaxf(m1, __shfl_xor(m1, 4));
                float s0 = expf(t0 - m0), s1 = expf(t1 - m1);
                s0 += __shfl_xor(s0, 1); s1 += __shfl_xor(s1, 1);
                s0 += __shfl_xor(s0, 2); s1 += __shfl_xor(s1, 2);
                s0 += __shfl_xor(s0, 4); s1 += __shfl_xor(s1, 4);
                laN0 = m0 + logf(s0) + sElp[b0l][ts][kf];
                laN1 = m1 + logf(s1) + sElp[b1l][ts][kf];
                laP0 = __shfl(laN0, jf << 3);   // redistribute la[j] for next step
                laP1 = __shfl(laN1, jf << 3);
            }
        }
        __syncthreads();
    }

    // argmax state (first-index on ties, like jnp.argmax)
    float bst0 = -INFINITY, bst1 = -INFINITY;
    int s00 = 0, s01 = 0;
#pragma unroll
    for (int k = 0; k < KK; ++k) {
        float v0 = __shfl(laN0, k * 8);
        float v1 = __shfl(laN1, k * 8);
        if (v0 > bst0) { bst0 = v0; s00 = k; }
        if (v1 > bst1) { bst1 = v1; s01 = k; }
    }

    // ---------------- Phase C: P-step autoregressive rollout ----------------
    const float4* Wv = reinterpret_cast<const float4*>(Wg);   // global, L1/L2-hot
    float* bf0 = &sBuf[b0l][0];
    float* bf1 = &sBuf[b1l][0];
    for (int p = 0; p < PP; ++p) {
        int sa = (int)sChain[s00][p];
        int sb = (int)sChain[s01][p];
        float4 x0 = bv0[64 + p + t];       // window [p, p+63] of rolling buffer
        float4 x1 = bv1[64 + p + t];
        float pr0[CCH], pr1[CCH];
#pragma unroll
        for (int c = 0; c < CCH; ++c) {
            float4 w0 = Wv[(sa * CCH + c) * LL + t];   // per-lane coalesced
            float4 w1 = Wv[(sb * CCH + c) * LL + t];
            pr0[c] = fmaf(x0.w, w0.w, fmaf(x0.z, w0.z, fmaf(x0.y, w0.y, x0.x * w0.x)));
            pr1[c] = fmaf(x1.w, w1.w, fmaf(x1.z, w1.z, fmaf(x1.y, w1.y, x1.x * w1.x)));
        }
#pragma unroll
        for (int c = 0; c < CCH; ++c) {
#pragma unroll
            for (int d = 1; d < 64; d <<= 1) {
                pr0[c] += __shfl_xor(pr0[c], d);
                pr1[c] += __shfl_xor(pr1[c], d);
            }
            pr0[c] += sMean[sa][c];
            pr1[c] += sMean[sb][c];
        }
        int cw = lane & 3;
        float v0 = (cw == 0) ? pr0[0] : (cw == 1) ? pr0[1] : (cw == 2) ? pr0[2] : pr0[3];
        float v1 = (cw == 0) ? pr1[0] : (cw == 1) ? pr1[1] : (cw == 2) ? pr1[2] : pr1[3];
        if (lane < 4) {
            bf0[(128 + p) * 4 + cw] = v0;                       // append pred to buffer
            out[(bBase + b0l) * (PP * CCH) + p * CCH + cw] = v0;
        } else if (lane < 8) {
            bf1[(128 + p) * 4 + cw] = v1;
            out[(bBase + b1l) * (PP * CCH) + p * CCH + cw] = v1;
        }
        __syncthreads();
    }
}

extern "C" void kernel_launch(void* const* d_in, const int* in_sizes, int n_in,
                              void* d_out, int out_size, void* d_ws, size_t ws_size,
                              hipStream_t stream) {
    (void)in_sizes; (void)n_in; (void)d_ws; (void)ws_size; (void)out_size;
    const float* em  = (const float*)d_in[0];
    const float* trm = (const float*)d_in[1];
    const float* ini = (const float*)d_in[2];
    const float* mns = (const float*)d_in[3];
    const float* cvc = (const float*)d_in[4];
    const float* Wg  = (const float*)d_in[5];
    float* out = (float*)d_out;
    dim3 grid(BB / BPB), block(NTHR);
    hipLaunchKernelGGL(lahmm_fused, grid, block, 0, stream,
                       em, trm, ini, mns, cvc, Wg, out);
}

// Round 5
// 281.704 us; speedup vs baseline: 1.1459x; 1.1459x over previous
//
#include <hip/hip_runtime.h>
#include <math.h>

// LinearAutoregressiveHMM fused kernel for MI355X (gfx950).
// B=8192, L=64, C=4, K=8, P=16.
// Block = 256 threads (4 waves); each wave owns 2 batch rows; 8 rows/block.
//
// R5 changes vs R4 (293us):
//  - Root cause across R1/R3/R4 (~290us): W reads on the per-CU LDS pipe
//    (2048 broadcast ds_reads/wave = 136-204us/CU). R2 (205us) was faster
//    because its wave-uniform GLOBAL W loads compiled to s_load on the
//    (idle) scalar pipe; R2 only lost to acc spills.
//  - So: W from global, uniform index (scalar pipe) + k-quarters (16 accs,
//    spill-free per R4). DS pipe now carries only x-reads -> Phase A is
//    VALU-bound at its ~55us FMA floor.
//  - Phase B rewritten: wave 0 only, lane=(b,k) covers all 8 b's; 8 shfl +
//    ~40 VALU per step (was 16 bpermutes per 2 b's -> ~40us/CU of DS).
//    Same balanced-tree sum/max association + expf/logf as passing rounds.
//  - sElp now full [t][b][k] (16KB), chunk staging deleted. LDS ~35.6KB.

namespace {
constexpr int BB   = 8192;
constexpr int LL   = 64;
constexpr int CCH  = 4;
constexpr int KK   = 8;
constexpr int PP   = 16;
constexpr int BPB  = 8;    // batch rows per block
constexpr int NTHR = 256;
}

__global__ __launch_bounds__(256)
void lahmm_fused(const float* __restrict__ em,  const float* __restrict__ trm,
                 const float* __restrict__ ini, const float* __restrict__ mns,
                 const float* __restrict__ cvc, const float* __restrict__ Wg,
                 float* __restrict__ out)
{
    __shared__ __align__(16) float sBuf[BPB][576];     // per b: 144 timesteps x 4 ch (18KB)
    __shared__ __align__(16) float sElp[LL][BPB][KK];  // [t][b][k] full (16KB)
    __shared__ float sLT[KK][KK];      // log(softmax(trans)+1e-8), [j][k]
    __shared__ float sLI[KK];          // log(softmax(init))
    __shared__ float sMean[KK][CCH];
    __shared__ float sVar[KK][CCH];
    __shared__ float sLogdet[KK];
    __shared__ int   sNs[KK];          // argmax of each trans row
    __shared__ int   sStateB[BPB];     // per-b argmax state after recursion
    __shared__ unsigned char sChain[KK][PP];  // state chain from each start state

    const int tid   = threadIdx.x;
    const int lane  = tid & 63;
    const int wv    = tid >> 6;
    const int bBase = blockIdx.x * BPB;

    // ---------------- Phase 0: stage emissions + small tables ----------------
    const float4* em4 = reinterpret_cast<const float4*>(em);
    float4* sBuf4 = reinterpret_cast<float4*>(&sBuf[0][0]);
#pragma unroll
    for (int r = 0; r < 2; ++r) {
        int idx = tid + r * 256;            // 0..511 covers 8 b x 64 rows
        int bl = idx >> 6, row = idx & 63;
        sBuf4[bl * 144 + 64 + row] = em4[(bBase + bl) * 64 + row];
        sBuf4[bl * 144 + row]      = make_float4(0.f, 0.f, 0.f, 0.f);
    }

    if (tid < KK) {
        // transition row tid: softmax -> log(+1e-8); next-state argmax (raw row: monotone)
        float row[KK];
        float m = -INFINITY;
#pragma unroll
        for (int k = 0; k < KK; ++k) { row[k] = trm[tid * KK + k]; m = fmaxf(m, row[k]); }
        float se = 0.f;
#pragma unroll
        for (int k = 0; k < KK; ++k) se += expf(row[k] - m);
        int best = 0; float bv = row[0];
#pragma unroll
        for (int k = 1; k < KK; ++k) if (row[k] > bv) { bv = row[k]; best = k; }
        sNs[tid] = best;
#pragma unroll
        for (int k = 0; k < KK; ++k) sLT[tid][k] = logf(expf(row[k] - m) / se + 1e-8f);
    } else if (tid == 8) {
        float x[KK]; float m = -INFINITY;
#pragma unroll
        for (int k = 0; k < KK; ++k) { x[k] = ini[k]; m = fmaxf(m, x[k]); }
        float se = 0.f;
#pragma unroll
        for (int k = 0; k < KK; ++k) se += expf(x[k] - m);
#pragma unroll
        for (int k = 0; k < KK; ++k) sLI[k] = logf(expf(x[k] - m) / se);
    } else if (tid >= 32 && tid < 64) {
        int i = tid - 32;                   // 0..31 covers K*C
        (&sMean[0][0])[i] = mns[i];
        (&sVar[0][0])[i]  = expf(cvc[i]) + 1e-6f;
    }
    __syncthreads();
    if (tid < KK) {
        float ld = 0.f;
#pragma unroll
        for (int c = 0; c < CCH; ++c) ld += logf(sVar[tid][c]);
        sLogdet[tid] = ld;
        int s = tid;
#pragma unroll
        for (int p = 0; p < PP; ++p) { s = sNs[s]; sChain[tid][p] = (unsigned char)s; }
    }
    __syncthreads();

    // ---------------- Phase A: AR scores (the 8.6 GFLOP conv) ----------------
    // 4 k-quarter passes (16 live accs). W from global with wave-uniform
    // addresses -> compiler scalarizes to s_load (scalar pipe, not DS pipe).
    const int b0l = wv * 2, b1l = wv * 2 + 1;
    const float4* bv0 = reinterpret_cast<const float4*>(&sBuf[b0l][0]);
    const float4* bv1 = reinterpret_cast<const float4*>(&sBuf[b1l][0]);
    const float4* Wg4 = reinterpret_cast<const float4*>(Wg);
    const int t = lane;   // lane owns output timestep t for both its b's

    float e0[KK], e1[KK];
    const float c2pi = 7.3515082656373819f;   // C * log(2*pi)

#pragma unroll
    for (int kq = 0; kq < 4; ++kq) {
        float acc0[2][CCH], acc1[2][CCH];
#pragma unroll
        for (int q = 0; q < 2; ++q)
#pragma unroll
            for (int c = 0; c < CCH; ++c) { acc0[q][c] = 0.f; acc1[q][c] = 0.f; }

#pragma unroll 2
        for (int j = 1; j < LL; ++j) {      // j=0 multiplies only the zero pad
            float4 x0 = bv0[t + j];         // per-lane contiguous b128
            float4 x1 = bv1[t + j];
#pragma unroll
            for (int q = 0; q < 2; ++q) {
#pragma unroll
                for (int c = 0; c < CCH; ++c) {
                    // uniform address -> s_load (scalar cache), SGPR operand in fma
                    float4 w = Wg4[((kq * 2 + q) * CCH + c) * LL + j];
                    float a0 = acc0[q][c], a1 = acc1[q][c];
                    a0 = fmaf(x0.x, w.x, a0); a1 = fmaf(x1.x, w.x, a1);
                    a0 = fmaf(x0.y, w.y, a0); a1 = fmaf(x1.y, w.y, a1);
                    a0 = fmaf(x0.z, w.z, a0); a1 = fmaf(x1.z, w.z, a1);
                    a0 = fmaf(x0.w, w.w, a0); a1 = fmaf(x1.w, w.w, a1);
                    acc0[q][c] = a0; acc1[q][c] = a1;
                }
            }
        }

        // emission log-probs for this k-quarter (numerics identical to R1-R4)
        float4 tg0 = bv0[64 + t], tg1 = bv1[64 + t];
#pragma unroll
        for (int q = 0; q < 2; ++q) {
            const int k = kq * 2 + q;       // compile-time (kq unrolled)
            float mh0 = 0.f, mh1 = 0.f;
#pragma unroll
            for (int c = 0; c < CCH; ++c) {
                float mu = sMean[k][c], va = sVar[k][c];
                float g0 = (c == 0) ? tg0.x : (c == 1) ? tg0.y : (c == 2) ? tg0.z : tg0.w;
                float g1 = (c == 0) ? tg1.x : (c == 1) ? tg1.y : (c == 2) ? tg1.z : tg1.w;
                float d0 = g0 - (mu + acc0[q][c]);
                float d1 = g1 - (mu + acc1[q][c]);
                mh0 += d0 * d0 / va;
                mh1 += d1 * d1 / va;
            }
            e0[k] = -0.5f * (mh0 + sLogdet[k] + c2pi);
            e1[k] = -0.5f * (mh1 + sLogdet[k] + c2pi);
        }
    }

    // store elp to full [t][b][k] staging (float4 x4 per lane)
    {
        float4* d0 = reinterpret_cast<float4*>(&sElp[t][b0l][0]);
        d0[0] = make_float4(e0[0], e0[1], e0[2], e0[3]);
        d0[1] = make_float4(e0[4], e0[5], e0[6], e0[7]);
        float4* d1 = reinterpret_cast<float4*>(&sElp[t][b1l][0]);
        d1[0] = make_float4(e1[0], e1[1], e1[2], e1[3]);
        d1[1] = make_float4(e1[4], e1[5], e1[6], e1[7]);
    }
    __syncthreads();

    // ---------------- Phase B: HMM forward recursion (wave 0 only) ----------------
    // lane = (b,k): b = lane>>3 (block-local batch row), k = lane&7.
    // Same balanced-tree max/sum association + expf/logf as passing rounds.
    if (wv == 0) {
        const int bb = lane >> 3, kb = lane & 7;
        const int gbase = lane & 0x38;      // lane of (bb, j=0)
        float ltT[KK];
#pragma unroll
        for (int j = 0; j < KK; ++j) ltT[j] = sLT[j][kb];
        float la = sLI[kb] + sElp[0][bb][kb];
        for (int ts = 1; ts < LL; ++ts) {
            float v0 = __shfl(la, gbase + 0) + ltT[0];
            float v1 = __shfl(la, gbase + 1) + ltT[1];
            float v2 = __shfl(la, gbase + 2) + ltT[2];
            float v3 = __shfl(la, gbase + 3) + ltT[3];
            float v4 = __shfl(la, gbase + 4) + ltT[4];
            float v5 = __shfl(la, gbase + 5) + ltT[5];
            float v6 = __shfl(la, gbase + 6) + ltT[6];
            float v7 = __shfl(la, gbase + 7) + ltT[7];
            float m = fmaxf(fmaxf(fmaxf(v0, v1), fmaxf(v2, v3)),
                            fmaxf(fmaxf(v4, v5), fmaxf(v6, v7)));
            float s = (expf(v0 - m) + expf(v1 - m)) + (expf(v2 - m) + expf(v3 - m))
                    + ((expf(v4 - m) + expf(v5 - m)) + (expf(v6 - m) + expf(v7 - m)));
            la = m + logf(s) + sElp[ts][bb][kb];
        }
        // argmax over k within the 8-lane group, first-index on ties
        float bv = la; int bi = kb;
#pragma unroll
        for (int d = 1; d < 8; d <<= 1) {
            float ov = __shfl_xor(bv, d);
            int   oi = __shfl_xor(bi, d);
            if (ov > bv || (ov == bv && oi < bi)) { bv = ov; bi = oi; }
        }
        if (kb == 0) sStateB[bb] = bi;
    }
    __syncthreads();

    // ---------------- Phase C: P-step autoregressive rollout ----------------
    const int s00 = sStateB[b0l];
    const int s01 = sStateB[b1l];
    const float4* Wv = reinterpret_cast<const float4*>(Wg);   // vector path, L2-hot
    float* bf0 = &sBuf[b0l][0];
    float* bf1 = &sBuf[b1l][0];
    for (int p = 0; p < PP; ++p) {
        int sa = (int)sChain[s00][p];
        int sb = (int)sChain[s01][p];
        float4 x0 = bv0[64 + p + t];       // window [p, p+63] of rolling buffer
        float4 x1 = bv1[64 + p + t];
        float pr0[CCH], pr1[CCH];
#pragma unroll
        for (int c = 0; c < CCH; ++c) {
            float4 w0 = Wv[(sa * CCH + c) * LL + t];   // per-lane coalesced
            float4 w1 = Wv[(sb * CCH + c) * LL + t];
            pr0[c] = fmaf(x0.w, w0.w, fmaf(x0.z, w0.z, fmaf(x0.y, w0.y, x0.x * w0.x)));
            pr1[c] = fmaf(x1.w, w1.w, fmaf(x1.z, w1.z, fmaf(x1.y, w1.y, x1.x * w1.x)));
        }
#pragma unroll
        for (int c = 0; c < CCH; ++c) {
#pragma unroll
            for (int d = 1; d < 64; d <<= 1) {
                pr0[c] += __shfl_xor(pr0[c], d);
                pr1[c] += __shfl_xor(pr1[c], d);
            }
            pr0[c] += sMean[sa][c];
            pr1[c] += sMean[sb][c];
        }
        int cw = lane & 3;
        float v0 = (cw == 0) ? pr0[0] : (cw == 1) ? pr0[1] : (cw == 2) ? pr0[2] : pr0[3];
        float v1 = (cw == 0) ? pr1[0] : (cw == 1) ? pr1[1] : (cw == 2) ? pr1[2] : pr1[3];
        if (lane < 4) {
            bf0[(128 + p) * 4 + cw] = v0;                       // append pred to buffer
            out[(bBase + b0l) * (PP * CCH) + p * CCH + cw] = v0;
        } else if (lane < 8) {
            bf1[(128 + p) * 4 + cw] = v1;
            out[(bBase + b1l) * (PP * CCH) + p * CCH + cw] = v1;
        }
        __syncthreads();
    }
}

extern "C" void kernel_launch(void* const* d_in, const int* in_sizes, int n_in,
                              void* d_out, int out_size, void* d_ws, size_t ws_size,
                              hipStream_t stream) {
    (void)in_sizes; (void)n_in; (void)d_ws; (void)ws_size; (void)out_size;
    const float* em  = (const float*)d_in[0];
    const float* trm = (const float*)d_in[1];
    const float* ini = (const float*)d_in[2];
    const float* mns = (const float*)d_in[3];
    const float* cvc = (const float*)d_in[4];
    const float* Wg  = (const float*)d_in[5];
    float* out = (float*)d_out;
    dim3 grid(BB / BPB), block(NTHR);
    hipLaunchKernelGGL(lahmm_fused, grid, block, 0, stream,
                       em, trm, ini, mns, cvc, Wg, out);
}